// Round 8
// baseline (20.220 us; speedup 1.0000x reference)
//
#include <hip/hip_runtime.h>
#include <math.h>

// probs/targets: (32,1,512,512) fp32
// ROUND 8: r7 post-mortem — T_p=8.8us vs 4.9 load floor was ~zero overlap
// (2 waves/SIMD, 4 serialized load->wait->compute phases). Fix:
//  (1) 1024 blocks x 32 elem/thread -> 4 waves/SIMD TLP
//  (2) front-load all 16 dwordx4 loads (one latency round trip, max MLP)
//  (3) cgt counted via ballot+popcount on the SALU pipe (off VALU, off butterfly)
#define NS 32
#define NELEM 262144
#define PBLK 32               // partial blocks per sample
#define GRID (NS * PBLK)      // 1024 blocks
#define TPB 256               // 4 waves
#define CHUNK (NELEM / PBLK)  // 8192 elements per block; 32 per thread

#define NPART (NS * PBLK)     // 1024 partial sets
#define OFF_S1   0
#define OFF_S2   (NPART * 1)
#define OFF_DOT  (NPART * 2)
#define OFF_MX   (NPART * 3)
#define OFF_CGT  (NPART * 4)  // int: count(p > 0.5)
#define OFF_PK   (NPART * 5)  // int: (cnt_at_max << 16) | gt_at_max

// branch-free (mx,pk) semigroup; 16-bit fields hold counts <= 8192 (block scope)
__device__ __forceinline__ void comb(float& mx, int& pk, float m2, int pk2) {
    const bool g = m2 > mx;
    const bool e = m2 == mx;
    pk = g ? pk2 : (pk + (e ? pk2 : 0));
    mx = fmaxf(mx, m2);
}

__global__ __launch_bounds__(TPB, 4) void k_partial(const float* __restrict__ probs,
                                                    const float* __restrict__ tgts,
                                                    float* __restrict__ wsf,
                                                    int* __restrict__ wsi) {
    const int b = blockIdx.x;
    const int s = b >> 5;           // sample
    const int c = b & (PBLK - 1);   // chunk within sample
    const size_t base = (size_t)s * NELEM + (size_t)c * CHUNK;
    const float4* __restrict__ p4 = (const float4*)(probs + base);
    const float4* __restrict__ t4 = (const float4*)(tgts + base);
    const int t = threadIdx.x;

    // ---- front-load ALL data: 16 back-to-back dwordx4 (64 VGPRs) ----
    float4 pv[2][4], tv[2][4];
#pragma unroll
    for (int g = 0; g < 2; ++g)
#pragma unroll
        for (int k = 0; k < 4; ++k) {
            const int idx = g * 1024 + k * 256 + t;
            pv[g][k] = p4[idx];
            tv[g][k] = t4[idx];
        }

    float4 a1 = {0.f,0.f,0.f,0.f}, a2 = {0.f,0.f,0.f,0.f}, ad = {0.f,0.f,0.f,0.f};
    float mxr = -INFINITY;
    int pkr = 0;
    int cgt_w = 0;                 // wave-uniform (ballot/popcount, SALU pipe)

#pragma unroll
    for (int g = 0; g < 2; ++g) {
        // sums — component-parallel, no scalar chains
#pragma unroll
        for (int k = 0; k < 4; ++k) {
            a1.x += pv[g][k].x; a1.y += pv[g][k].y; a1.z += pv[g][k].z; a1.w += pv[g][k].w;
            a2.x += tv[g][k].x; a2.y += tv[g][k].y; a2.z += tv[g][k].z; a2.w += tv[g][k].w;
            ad.x = fmaf(pv[g][k].x, tv[g][k].x, ad.x);
            ad.y = fmaf(pv[g][k].y, tv[g][k].y, ad.y);
            ad.z = fmaf(pv[g][k].z, tv[g][k].z, ad.z);
            ad.w = fmaf(pv[g][k].w, tv[g][k].w, ad.w);
        }

        // group max via pairwise tree (depth 4)
        const float m01x = fmaxf(tv[g][0].x, tv[g][1].x), m23x = fmaxf(tv[g][2].x, tv[g][3].x);
        const float m01y = fmaxf(tv[g][0].y, tv[g][1].y), m23y = fmaxf(tv[g][2].y, tv[g][3].y);
        const float m01z = fmaxf(tv[g][0].z, tv[g][1].z), m23z = fmaxf(tv[g][2].z, tv[g][3].z);
        const float m01w = fmaxf(tv[g][0].w, tv[g][1].w), m23w = fmaxf(tv[g][2].w, tv[g][3].w);
        const float mg = fmaxf(fmaxf(fmaxf(m01x, m23x), fmaxf(m01y, m23y)),
                               fmaxf(fmaxf(m01z, m23z), fmaxf(m01w, m23w)));

        // recount vs group max; cgt via wave ballot (SALU popcount)
        int cg = 0, gg = 0;
#pragma unroll
        for (int k = 0; k < 4; ++k) {
            const float pc[4] = {pv[g][k].x, pv[g][k].y, pv[g][k].z, pv[g][k].w};
            const float tc[4] = {tv[g][k].x, tv[g][k].y, tv[g][k].z, tv[g][k].w};
#pragma unroll
            for (int j = 0; j < 4; ++j) {
                const bool b1 = pc[j] > 0.5f;
                const bool eq = tc[j] == mg;
                cgt_w += (int)__popcll(__ballot(b1));   // wave-collective, scalar add
                cg += eq;
                gg += eq && b1;
            }
        }
        comb(mxr, pkr, mg, (cg << 16) | gg);
    }

    float s1 = (a1.x + a1.y) + (a1.z + a1.w);
    float s2 = (a2.x + a2.y) + (a2.z + a2.w);
    float dt = (ad.x + ad.y) + (ad.z + ad.w);

    // wave butterfly: 5 quantities x 6 levels (cgt is already wave-level)
#pragma unroll
    for (int off = 32; off; off >>= 1) {
        s1 += __shfl_xor(s1, off);
        s2 += __shfl_xor(s2, off);
        dt += __shfl_xor(dt, off);
        const float m2 = __shfl_xor(mxr, off);
        const int  pk2 = __shfl_xor(pkr, off);
        comb(mxr, pkr, m2, pk2);
    }

    // cross-wave via LDS (4 waves)
    __shared__ float ls1[4], ls2[4], ldt[4], lmx[4];
    __shared__ int   lcg[4], lpk[4];
    const int w = t >> 6, lane = t & 63;
    if (lane == 0) {
        ls1[w] = s1; ls2[w] = s2; ldt[w] = dt; lmx[w] = mxr;
        lcg[w] = cgt_w; lpk[w] = pkr;
    }
    __syncthreads();
    if (t == 0) {
        int cgt = cgt_w;
#pragma unroll
        for (int w2 = 1; w2 < TPB / 64; ++w2) {
            s1 += ls1[w2]; s2 += ls2[w2]; dt += ldt[w2]; cgt += lcg[w2];
            comb(mxr, pkr, lmx[w2], lpk[w2]);
        }
        wsf[OFF_S1  + b] = s1;
        wsf[OFF_S2  + b] = s2;
        wsf[OFF_DOT + b] = dt;
        wsf[OFF_MX  + b] = mxr;
        wsi[OFF_CGT + b] = cgt;
        wsi[OFF_PK  + b] = pkr;
    }
}

__device__ __forceinline__ void combine_max(float& mx, int& cnt, int& gt,
                                            float mx2, int cnt2, int gt2) {
    if (mx2 > mx) { mx = mx2; cnt = cnt2; gt = gt2; }
    else if (mx2 == mx) { cnt += cnt2; gt += gt2; }
}

// finalize + mean: 1024 threads (16 waves); wave w reduces samples 2w,2w+1
// (32 partials each, one per lane of each 32-lane half).
__global__ __launch_bounds__(1024) void k_final(const float* __restrict__ wsf,
                                                const int* __restrict__ wsi,
                                                float* __restrict__ out) {
    __shared__ float scores[NS];
    const int t = threadIdx.x;
    const int w = t >> 6, lane = t & 63;
    const int samp = 2 * w + (lane >> 5);
    const int pidx = lane & 31;
    const int idx = samp * PBLK + pidx;

    float s1  = wsf[OFF_S1  + idx];
    float s2  = wsf[OFF_S2  + idx];
    float dot = wsf[OFF_DOT + idx];
    float mx  = wsf[OFF_MX  + idx];
    int   cgt = wsi[OFF_CGT + idx];
    const int pk = wsi[OFF_PK + idx];
    int   cnt = pk >> 16;      // unpack: sample-level counts exceed 16 bits
    int   gt  = pk & 0xFFFF;

#pragma unroll
    for (int off = 16; off; off >>= 1) {   // stays within 32-lane group
        s1  += __shfl_xor(s1, off);
        s2  += __shfl_xor(s2, off);
        dot += __shfl_xor(dot, off);
        cgt += __shfl_xor(cgt, off);
        float m2 = __shfl_xor(mx, off);
        int   c2 = __shfl_xor(cnt, off);
        int   g2 = __shfl_xor(gt, off);
        combine_max(mx, cnt, gt, m2, c2, g2);
    }

    if (pidx == 0) {
        const int cle = NELEM - cgt;       // count(p <= 0.5)
        const long long corr = (long long)cle - (long long)cnt + 2LL * (long long)gt;
        float score = 2.0f * (dot + 1.0f) / (s1 + s2 + 1.0f);
        if (corr == 1) score = 1.0f;       // acc == 1.0 (probs.shape[1] == 1)
        scores[samp] = 1.0f - score;
    }

    __syncthreads();
    if (t < 64) {
        float v = (t < NS) ? scores[t] : 0.0f;
#pragma unroll
        for (int off = 32; off; off >>= 1) v += __shfl_xor(v, off);
        if (t == 0) out[0] = v * (1.0f / (float)NS);
    }
}

extern "C" void kernel_launch(void* const* d_in, const int* in_sizes, int n_in,
                              void* d_out, int out_size, void* d_ws, size_t ws_size,
                              hipStream_t stream) {
    const float* probs = (const float*)d_in[0];
    const float* tgts  = (const float*)d_in[1];
    float* wsf = (float*)d_ws;
    int*   wsi = (int*)d_ws;
    float* out = (float*)d_out;

    k_partial<<<GRID, TPB, 0, stream>>>(probs, tgts, wsf, wsi);
    k_final<<<1, 1024, 0, stream>>>(wsf, wsi, out);
}

// Round 9
// 19.141 us; speedup vs baseline: 1.0563x; 1.0563x over previous
//
#include <hip/hip_runtime.h>
#include <math.h>

// probs/targets: (32,1,512,512) fp32
// ROUND 9: r7 + ONE lever — register double-buffer prefetch. r7's T_p=8.6us
// vs 4.9 load floor = exposed L3 latency from 4 serial load->wait->compute
// phases at 2 waves/SIMD. Issue group g+1 loads before computing group g
// (static A/B names). Everything else identical to r7 (best = 19.26us).
#define NS 32
#define NELEM 262144
#define PBLK 16               // partial blocks per sample
#define GRID (NS * PBLK)      // 512 blocks
#define TPB 256               // 4 waves
#define CHUNK (NELEM / PBLK)  // 16384 elements per block; 64 per thread

#define NPART (NS * PBLK)     // 512 partial sets
#define OFF_S1   0
#define OFF_S2   (NPART * 1)
#define OFF_DOT  (NPART * 2)
#define OFF_MX   (NPART * 3)
#define OFF_CGT  (NPART * 4)  // int: count(p > 0.5)
#define OFF_PK   (NPART * 5)  // int: (cnt_at_max << 16) | gt_at_max

// branch-free (mx,pk) semigroup combine; 16-bit fields hold block-scope counts
__device__ __forceinline__ void comb(float& mx, int& pk, float m2, int pk2) {
    const bool g = m2 > mx;
    const bool e = m2 == mx;
    pk = g ? pk2 : (pk + (e ? pk2 : 0));
    mx = fmaxf(mx, m2);
}

struct Acc {
    float4 a1, a2, ad;
    int cgt;
    float mx;
    int pk;
};

__device__ __forceinline__ void consume(Acc& A, const float4 (&pv)[4],
                                        const float4 (&tv)[4]) {
    // sums — component-parallel, no scalar chains
#pragma unroll
    for (int k = 0; k < 4; ++k) {
        A.a1.x += pv[k].x; A.a1.y += pv[k].y; A.a1.z += pv[k].z; A.a1.w += pv[k].w;
        A.a2.x += tv[k].x; A.a2.y += tv[k].y; A.a2.z += tv[k].z; A.a2.w += tv[k].w;
        A.ad.x = fmaf(pv[k].x, tv[k].x, A.ad.x);
        A.ad.y = fmaf(pv[k].y, tv[k].y, A.ad.y);
        A.ad.z = fmaf(pv[k].z, tv[k].z, A.ad.z);
        A.ad.w = fmaf(pv[k].w, tv[k].w, A.ad.w);
    }
    // group max via pairwise tree (depth 4)
    const float mX = fmaxf(fmaxf(tv[0].x, tv[1].x), fmaxf(tv[2].x, tv[3].x));
    const float mY = fmaxf(fmaxf(tv[0].y, tv[1].y), fmaxf(tv[2].y, tv[3].y));
    const float mZ = fmaxf(fmaxf(tv[0].z, tv[1].z), fmaxf(tv[2].z, tv[3].z));
    const float mW = fmaxf(fmaxf(tv[0].w, tv[1].w), fmaxf(tv[2].w, tv[3].w));
    const float mg = fmaxf(fmaxf(mX, mY), fmaxf(mZ, mW));
    // branch-free recount vs group max
    int cp = 0, cg = 0, gg = 0;
#pragma unroll
    for (int k = 0; k < 4; ++k) {
        const float pc[4] = {pv[k].x, pv[k].y, pv[k].z, pv[k].w};
        const float tc[4] = {tv[k].x, tv[k].y, tv[k].z, tv[k].w};
#pragma unroll
        for (int j = 0; j < 4; ++j) {
            const int b1 = pc[j] > 0.5f;
            const int eq = tc[j] == mg;
            cp += b1;
            cg += eq;
            gg += eq & b1;
        }
    }
    A.cgt += cp;
    comb(A.mx, A.pk, mg, (cg << 16) | gg);
}

__global__ __launch_bounds__(TPB) void k_partial(const float* __restrict__ probs,
                                                 const float* __restrict__ tgts,
                                                 float* __restrict__ wsf,
                                                 int* __restrict__ wsi) {
    const int b = blockIdx.x;
    const int s = b >> 4;           // sample
    const int c = b & (PBLK - 1);   // chunk within sample
    const size_t base = (size_t)s * NELEM + (size_t)c * CHUNK;
    const float4* __restrict__ p4 = (const float4*)(probs + base);
    const float4* __restrict__ t4 = (const float4*)(tgts + base);
    const int t = threadIdx.x;

    Acc A;
    A.a1 = {0.f,0.f,0.f,0.f}; A.a2 = {0.f,0.f,0.f,0.f}; A.ad = {0.f,0.f,0.f,0.f};
    A.cgt = 0; A.mx = -INFINITY; A.pk = 0;

    // register double-buffer: issue next group's loads before computing current
    float4 pA[4], tA[4], pB[4], tB[4];

#pragma unroll
    for (int k = 0; k < 4; ++k) { pA[k] = p4[0*1024 + k*256 + t]; tA[k] = t4[0*1024 + k*256 + t]; }
#pragma unroll
    for (int k = 0; k < 4; ++k) { pB[k] = p4[1*1024 + k*256 + t]; tB[k] = t4[1*1024 + k*256 + t]; }
    consume(A, pA, tA);                      // G0 (while G1 in flight)
#pragma unroll
    for (int k = 0; k < 4; ++k) { pA[k] = p4[2*1024 + k*256 + t]; tA[k] = t4[2*1024 + k*256 + t]; }
    consume(A, pB, tB);                      // G1 (while G2 in flight)
#pragma unroll
    for (int k = 0; k < 4; ++k) { pB[k] = p4[3*1024 + k*256 + t]; tB[k] = t4[3*1024 + k*256 + t]; }
    consume(A, pA, tA);                      // G2 (while G3 in flight)
    consume(A, pB, tB);                      // G3

    float s1 = (A.a1.x + A.a1.y) + (A.a1.z + A.a1.w);
    float s2 = (A.a2.x + A.a2.y) + (A.a2.z + A.a2.w);
    float dt = (A.ad.x + A.ad.y) + (A.ad.z + A.ad.w);
    int cgt = A.cgt;
    float mxr = A.mx;
    int pkr = A.pk;

    // wave butterfly: 6 quantities x 6 levels
#pragma unroll
    for (int off = 32; off; off >>= 1) {
        s1  += __shfl_xor(s1, off);
        s2  += __shfl_xor(s2, off);
        dt  += __shfl_xor(dt, off);
        cgt += __shfl_xor(cgt, off);
        const float m2 = __shfl_xor(mxr, off);
        const int  pk2 = __shfl_xor(pkr, off);
        comb(mxr, pkr, m2, pk2);
    }

    // cross-wave via LDS (4 waves)
    __shared__ float ls1[4], ls2[4], ldt[4], lmx[4];
    __shared__ int   lcg[4], lpk[4];
    const int w = t >> 6, lane = t & 63;
    if (lane == 0) {
        ls1[w] = s1; ls2[w] = s2; ldt[w] = dt; lmx[w] = mxr;
        lcg[w] = cgt; lpk[w] = pkr;
    }
    __syncthreads();
    if (t == 0) {
#pragma unroll
        for (int w2 = 1; w2 < TPB / 64; ++w2) {
            s1 += ls1[w2]; s2 += ls2[w2]; dt += ldt[w2]; cgt += lcg[w2];
            comb(mxr, pkr, lmx[w2], lpk[w2]);
        }
        wsf[OFF_S1  + b] = s1;
        wsf[OFF_S2  + b] = s2;
        wsf[OFF_DOT + b] = dt;
        wsf[OFF_MX  + b] = mxr;
        wsi[OFF_CGT + b] = cgt;
        wsi[OFF_PK  + b] = pkr;
    }
}

__device__ __forceinline__ void combine_max(float& mx, int& cnt, int& gt,
                                            float mx2, int cnt2, int gt2) {
    if (mx2 > mx) { mx = mx2; cnt = cnt2; gt = gt2; }
    else if (mx2 == mx) { cnt += cnt2; gt += gt2; }
}

// finalize + mean: 512 threads (8 waves); each 16-lane group reduces one
// sample's 16 partials (segmented butterfly, offsets 8/4/2/1)
__global__ __launch_bounds__(512) void k_final(const float* __restrict__ wsf,
                                               const int* __restrict__ wsi,
                                               float* __restrict__ out) {
    __shared__ float scores[NS];
    const int t = threadIdx.x;
    const int w = t >> 6, lane = t & 63;
    const int samp = (w << 2) + (lane >> 4);  // 8 waves x 4 samples
    const int pidx = lane & 15;
    const int idx = samp * PBLK + pidx;

    float s1  = wsf[OFF_S1  + idx];
    float s2  = wsf[OFF_S2  + idx];
    float dot = wsf[OFF_DOT + idx];
    float mx  = wsf[OFF_MX  + idx];
    int   cgt = wsi[OFF_CGT + idx];
    const int pk = wsi[OFF_PK + idx];
    int   cnt = pk >> 16;      // unpack: sample-level counts exceed 16 bits
    int   gt  = pk & 0xFFFF;

#pragma unroll
    for (int off = 8; off; off >>= 1) {      // stays within 16-lane group
        s1  += __shfl_xor(s1, off);
        s2  += __shfl_xor(s2, off);
        dot += __shfl_xor(dot, off);
        cgt += __shfl_xor(cgt, off);
        float m2 = __shfl_xor(mx, off);
        int   c2 = __shfl_xor(cnt, off);
        int   g2 = __shfl_xor(gt, off);
        combine_max(mx, cnt, gt, m2, c2, g2);
    }

    if (pidx == 0) {
        const int cle = NELEM - cgt;         // count(p <= 0.5)
        const long long corr = (long long)cle - (long long)cnt + 2LL * (long long)gt;
        float score = 2.0f * (dot + 1.0f) / (s1 + s2 + 1.0f);
        if (corr == 1) score = 1.0f;         // acc == 1.0 (probs.shape[1] == 1)
        scores[samp] = 1.0f - score;
    }

    __syncthreads();
    if (t < 64) {
        float v = (t < NS) ? scores[t] : 0.0f;
#pragma unroll
        for (int off = 32; off; off >>= 1) v += __shfl_xor(v, off);
        if (t == 0) out[0] = v * (1.0f / (float)NS);
    }
}

extern "C" void kernel_launch(void* const* d_in, const int* in_sizes, int n_in,
                              void* d_out, int out_size, void* d_ws, size_t ws_size,
                              hipStream_t stream) {
    const float* probs = (const float*)d_in[0];
    const float* tgts  = (const float*)d_in[1];
    float* wsf = (float*)d_ws;
    int*   wsi = (int*)d_ws;
    float* out = (float*)d_out;

    k_partial<<<GRID, TPB, 0, stream>>>(probs, tgts, wsf, wsi);
    k_final<<<1, 512, 0, stream>>>(wsf, wsi, out);
}